// Round 1
// baseline (2099.431 us; speedup 1.0000x reference)
//
#include <hip/hip_runtime.h>
#include <hip/hip_bf16.h>
#include <math.h>

#define N_NODES 100000
#define N_EDGES 3200000
#define NODE_IN 118
#define DIM 32
#define EDF 53
#define NLAYER 4

typedef __attribute__((ext_vector_type(8))) short short8;
typedef __attribute__((ext_vector_type(4))) float f32x4;
typedef unsigned short u16;

static __device__ __forceinline__ float bf2f(u16 u) {
    union { unsigned int i; float f; } x; x.i = ((unsigned int)u) << 16; return x.f;
}
static __device__ __forceinline__ u16 f2bf(float f) {
    union { float f; unsigned int i; } x; x.f = f;
    unsigned int i = x.i;
    return (u16)((i + 0x7FFFu + ((i >> 16) & 1u)) >> 16);
}

// ---------------- CSR build ----------------
__global__ __launch_bounds__(256) void k_count(const int* __restrict__ dst, int* __restrict__ cnt) {
    int e = blockIdx.x * 256 + threadIdx.x;
    atomicAdd(&cnt[dst[e]], 1);
}

__global__ __launch_bounds__(256) void k_scanA(const int* __restrict__ cnt, int* __restrict__ off,
                                               int* __restrict__ bsum) {
    __shared__ int s[256];
    int t = threadIdx.x; int i = blockIdx.x * 256 + t;
    int v = (i < N_NODES) ? cnt[i] : 0;
    s[t] = v; __syncthreads();
    for (int d = 1; d < 256; d <<= 1) {
        int x = (t >= d) ? s[t - d] : 0; __syncthreads();
        s[t] += x; __syncthreads();
    }
    if (i < N_NODES) off[i] = s[t] - v;
    if (t == 255) bsum[blockIdx.x] = s[t];
}

__global__ __launch_bounds__(512) void k_scanB(int* bsum, int nb) {
    __shared__ int s[512];
    int t = threadIdx.x;
    int v = (t < nb) ? bsum[t] : 0;
    s[t] = v; __syncthreads();
    for (int d = 1; d < 512; d <<= 1) {
        int x = (t >= d) ? s[t - d] : 0; __syncthreads();
        s[t] += x; __syncthreads();
    }
    if (t < nb) bsum[t] = s[t] - v;
}

__global__ __launch_bounds__(256) void k_scanC(int* off, const int* __restrict__ bsum) {
    int i = blockIdx.x * 256 + threadIdx.x;
    if (i < N_NODES) off[i] += bsum[blockIdx.x];
    if (i == 0) off[N_NODES] = N_EDGES;
}

__global__ __launch_bounds__(256) void k_fill(const int* __restrict__ src, const int* __restrict__ dst,
                                              const int* __restrict__ off, int* __restrict__ cur,
                                              int* __restrict__ eidx, int* __restrict__ esrc) {
    int e = blockIdx.x * 256 + threadIdx.x;
    int d = dst[e];
    int p = off[d] + atomicAdd(&cur[d], 1);
    eidx[p] = e; esrc[p] = src[e];
}

// ---------------- node input projection: h = x @ W + b ----------------
__global__ __launch_bounds__(256) void k_init(const float* __restrict__ x, const float* __restrict__ W,
                                              const float* __restrict__ b, float* __restrict__ h) {
    __shared__ float Ws[NODE_IN * DIM];
    __shared__ float xs[8][NODE_IN];
    int t = threadIdx.x;
    for (int i = t; i < NODE_IN * DIM; i += 256) Ws[i] = W[i];
    int nb = blockIdx.x * 8;
    for (int i = t; i < 8 * NODE_IN; i += 256) {
        int n = i / NODE_IN, j = i % NODE_IN;
        xs[n][j] = x[(size_t)(nb + n) * NODE_IN + j];
    }
    __syncthreads();
    int n = t >> 5, c = t & 31;
    float acc = b[c];
    #pragma unroll 2
    for (int j = 0; j < NODE_IN; j++) acc += xs[n][j] * Ws[j * DIM + c];
    h[(size_t)(nb + n) * DIM + c] = acc;
}

// ---------------- edge-feature GEMM: e[l] = ef @ We[l], bf16 MFMA ----------------
template <int NL>
__global__ __launch_bounds__(256) void k_egemm(const float* __restrict__ elen, const float* __restrict__ evec,
                                               const float* __restrict__ We, u16* __restrict__ eout) {
    int lane = threadIdx.x & 63;
    int wv = (blockIdx.x * 256 + threadIdx.x) >> 6;
    int nwaves = (gridDim.x * 256) >> 6;
    int n15 = lane & 15, kb = lane >> 4;

    // B fragments: We padded to K=64, held in VGPRs for the whole kernel.
    short8 bf[2][2 * NL];
    for (int s = 0; s < 2; s++) {
        for (int tt = 0; tt < 2 * NL; tt++) {
            int n = tt * 16 + n15;
            int lay = n >> 5, c = n & 31;
            short8 tmp;
            #pragma unroll
            for (int j = 0; j < 8; j++) {
                int kk = s * 32 + kb * 8 + j;
                float w = (kk < EDF) ? We[(size_t)lay * EDF * DIM + kk * DIM + c] : 0.f;
                ((u16*)&tmp)[j] = f2bf(w);
            }
            bf[s][tt] = tmp;
        }
    }

    const int NT = N_EDGES / 16;
    for (int tile = wv; tile < NT; tile += nwaves) {
        int row = tile * 16 + n15;
        const float* lp = elen + (size_t)row * 50;
        const float* vp = evec + (size_t)row * 3;
        short8 af[2];
        #pragma unroll
        for (int s = 0; s < 2; s++) {
            int k0 = s * 32 + kb * 8;
            float fv[8];
            if (k0 <= 40) {
                const float2* p2 = (const float2*)(lp + k0);  // 8B aligned: row*200 + k0*4
                #pragma unroll
                for (int j2 = 0; j2 < 4; j2++) { float2 t2 = p2[j2]; fv[2*j2] = t2.x; fv[2*j2+1] = t2.y; }
            } else if (k0 == 48) {
                fv[0] = lp[48]; fv[1] = lp[49]; fv[2] = vp[0]; fv[3] = vp[1]; fv[4] = vp[2];
                fv[5] = 0.f; fv[6] = 0.f; fv[7] = 0.f;
            } else {
                #pragma unroll
                for (int j = 0; j < 8; j++) fv[j] = 0.f;
            }
            short8 tmp;
            #pragma unroll
            for (int j = 0; j < 8; j++) ((u16*)&tmp)[j] = f2bf(fv[j]);
            af[s] = tmp;
        }
        #pragma unroll
        for (int tt = 0; tt < 2 * NL; tt++) {
            f32x4 z = {0.f, 0.f, 0.f, 0.f};
            z = __builtin_amdgcn_mfma_f32_16x16x32_bf16(af[0], bf[0][tt], z, 0, 0, 0);
            z = __builtin_amdgcn_mfma_f32_16x16x32_bf16(af[1], bf[1][tt], z, 0, 0, 0);
            // C layout: col = lane&15 (n), row = (lane>>4)*4 + r (m)  [m89]
            int n = tt * 16 + n15;
            int lay = n >> 5, c = n & 31;
            size_t base = ((size_t)lay * N_EDGES + (size_t)tile * 16) * DIM;
            #pragma unroll
            for (int r = 0; r < 4; r++) {
                int m = kb * 4 + r;
                eout[base + (size_t)m * DIM + c] = f2bf(z[r]);
            }
        }
    }
}

// ---------------- per-layer node transform: LN + q,k,v,skip ----------------
__global__ __launch_bounds__(256) void k_node(const float* __restrict__ h,
        const float* __restrict__ g, const float* __restrict__ bta,
        const float* __restrict__ Wq, const float* __restrict__ bq,
        const float* __restrict__ Wk, const float* __restrict__ bk,
        const float* __restrict__ Wv, const float* __restrict__ bv,
        const float* __restrict__ Ws, const float* __restrict__ bs,
        float* __restrict__ qo, float* __restrict__ ko, float* __restrict__ vo, float* __restrict__ so) {
    __shared__ float WQ[DIM * DIM], WK[DIM * DIM], WV[DIM * DIM], WS[DIM * DIM];
    __shared__ float xn[8][DIM];
    int t = threadIdx.x;
    for (int i = t; i < DIM * DIM; i += 256) { WQ[i] = Wq[i]; WK[i] = Wk[i]; WV[i] = Wv[i]; WS[i] = Ws[i]; }
    int n = t >> 5, c = t & 31;
    size_t node = (size_t)blockIdx.x * 8 + n;
    float hv = h[node * DIM + c];
    float s1 = hv;
    for (int d = 1; d < 32; d <<= 1) s1 += __shfl_xor(s1, d, 64);
    float mu = s1 * (1.f / 32.f);
    float dv = hv - mu;
    float s2 = dv * dv;
    for (int d = 1; d < 32; d <<= 1) s2 += __shfl_xor(s2, d, 64);
    float inv = rsqrtf(s2 * (1.f / 32.f) + 1e-5f);
    float xv = dv * inv * g[c] + bta[c];
    xn[n][c] = xv;
    __syncthreads();
    float aq = bq[c], ak = bk[c], av = bv[c], as = bs[c];
    #pragma unroll 4
    for (int j = 0; j < DIM; j++) {
        float xj = xn[n][j];
        aq += xj * WQ[j * DIM + c];
        ak += xj * WK[j * DIM + c];
        av += xj * WV[j * DIM + c];
        as += xj * WS[j * DIM + c];
    }
    size_t o = node * DIM + c;
    qo[o] = aq; ko[o] = ak; vo[o] = av; so[o] = as;
}

// ---------------- per-layer edge aggregation (node-centric, fused softmax) ----------------
__global__ __launch_bounds__(256) void k_aggr(const int* __restrict__ off, const int* __restrict__ eidx,
        const int* __restrict__ esrc, const u16* __restrict__ eb,
        const float* __restrict__ qb, const float* __restrict__ kb, const float* __restrict__ vb,
        const float* __restrict__ h, const float* __restrict__ sk, float* __restrict__ out) {
    int t = threadIdx.x;
    size_t node = (size_t)blockIdx.x * 8 + (t >> 5);
    int c = t & 31;
    float qc = qb[node * DIM + c];
    int o0 = off[node], o1 = off[node + 1];
    float num = 0.f, den = 0.f;
    const float scale = 0.35355339059327373f;  // 1/sqrt(8)
    for (int p = o0; p < o1; p++) {
        int eid = eidx[p], sj = esrc[p];
        float ev = bf2f(eb[(size_t)eid * DIM + c]);
        float kv = kb[(size_t)sj * DIM + c];
        float a = qc * (kv + ev);
        a += __shfl_xor(a, 1); a += __shfl_xor(a, 2); a += __shfl_xor(a, 4);
        float ex = __expf(a * scale);
        float vv = vb[(size_t)sj * DIM + c];
        num += ex * (vv + ev);
        den += ex;
    }
    float agg = num / (den + 1e-16f);
    size_t o = node * DIM + c;
    out[o] = h[o] + agg + sk[o];
}

extern "C" void kernel_launch(void* const* d_in, const int* in_sizes, int n_in,
                              void* d_out, int out_size, void* d_ws, size_t ws_size,
                              hipStream_t stream) {
    const float* x    = (const float*)d_in[0];
    const int*   ei   = (const int*)d_in[1];
    const int*   src  = ei;
    const int*   dst  = ei + N_EDGES;
    const float* elen = (const float*)d_in[2];
    const float* evec = (const float*)d_in[3];
    const float* niW  = (const float*)d_in[4];
    const float* nib  = (const float*)d_in[5];
    const float* lng  = (const float*)d_in[6];
    const float* lnb  = (const float*)d_in[7];
    const float* Wq   = (const float*)d_in[8];
    const float* bq   = (const float*)d_in[9];
    const float* Wk   = (const float*)d_in[10];
    const float* bk   = (const float*)d_in[11];
    const float* Wv   = (const float*)d_in[12];
    const float* bv   = (const float*)d_in[13];
    const float* We   = (const float*)d_in[14];
    const float* Wsk  = (const float*)d_in[15];
    const float* bsk  = (const float*)d_in[16];
    float* out = (float*)d_out;

    unsigned char* w = (unsigned char*)d_ws;
    auto alloc = [&](size_t bytes) -> void* {
        void* p = (void*)w; w += (bytes + 255) & ~(size_t)255; return p;
    };
    int*   off  = (int*)alloc((N_NODES + 1) * sizeof(int));
    int*   cnt  = (int*)alloc(N_NODES * sizeof(int));       // reused as cursor
    int*   bsum = (int*)alloc(512 * sizeof(int));
    int*   eidx = (int*)alloc((size_t)N_EDGES * sizeof(int));
    int*   esrc = (int*)alloc((size_t)N_EDGES * sizeof(int));
    float* h    = (float*)alloc((size_t)N_NODES * DIM * sizeof(float));
    float* qb   = (float*)alloc((size_t)N_NODES * DIM * sizeof(float));
    float* kb   = (float*)alloc((size_t)N_NODES * DIM * sizeof(float));
    float* vb   = (float*)alloc((size_t)N_NODES * DIM * sizeof(float));
    float* skb  = (float*)alloc((size_t)N_NODES * DIM * sizeof(float));
    size_t used = (size_t)(w - (unsigned char*)d_ws);
    size_t e_full = (size_t)NLAYER * N_EDGES * DIM * sizeof(u16);
    size_t e_one  = (size_t)N_EDGES * DIM * sizeof(u16);
    bool full = (used + e_full) <= ws_size;
    u16* ebuf = (u16*)alloc(full ? e_full : e_one);

    const int EB = N_EDGES / 256;   // 12500
    const int NB = N_NODES / 8;     // 12500
    const int nbScan = (N_NODES + 255) / 256;  // 391

    // CSR build
    hipMemsetAsync(cnt, 0, N_NODES * sizeof(int), stream);
    k_count<<<EB, 256, 0, stream>>>(dst, cnt);
    k_scanA<<<nbScan, 256, 0, stream>>>(cnt, off, bsum);
    k_scanB<<<1, 512, 0, stream>>>(bsum, nbScan);
    k_scanC<<<nbScan, 256, 0, stream>>>(off, bsum);
    hipMemsetAsync(cnt, 0, N_NODES * sizeof(int), stream);
    k_fill<<<EB, 256, 0, stream>>>(src, dst, off, cnt, eidx, esrc);

    // input projection
    k_init<<<NB, 256, 0, stream>>>(x, niW, nib, h);

    // edge-feature GEMM
    if (full) k_egemm<4><<<2048, 256, 0, stream>>>(elen, evec, We, ebuf);

    for (int l = 0; l < NLAYER; l++) {
        if (!full) k_egemm<1><<<2048, 256, 0, stream>>>(elen, evec, We + (size_t)l * EDF * DIM, ebuf);
        k_node<<<NB, 256, 0, stream>>>(h, lng + l * DIM, lnb + l * DIM,
                                       Wq + (size_t)l * DIM * DIM, bq + l * DIM,
                                       Wk + (size_t)l * DIM * DIM, bk + l * DIM,
                                       Wv + (size_t)l * DIM * DIM, bv + l * DIM,
                                       Wsk + (size_t)l * DIM * DIM, bsk + l * DIM,
                                       qb, kb, vb, skb);
        const u16* el = full ? (ebuf + (size_t)l * N_EDGES * DIM) : ebuf;
        k_aggr<<<NB, 256, 0, stream>>>(off, eidx, esrc, el, qb, kb, vb, h, skb,
                                       (l == NLAYER - 1) ? out : h);
    }
}

// Round 2
// 1870.429 us; speedup vs baseline: 1.1224x; 1.1224x over previous
//
#include <hip/hip_runtime.h>
#include <hip/hip_bf16.h>
#include <math.h>

#define N_NODES 100000
#define N_EDGES 3200000
#define NODE_IN 118
#define DIM 32
#define EDF 53
#define NLAYER 4

typedef __attribute__((ext_vector_type(8))) short short8;
typedef __attribute__((ext_vector_type(4))) float f32x4;
typedef unsigned short u16;

static __device__ __forceinline__ float bf2f(u16 u) {
    union { unsigned int i; float f; } x; x.i = ((unsigned int)u) << 16; return x.f;
}
static __device__ __forceinline__ u16 f2bf(float f) {
    union { float f; unsigned int i; } x; x.f = f;
    unsigned int i = x.i;
    return (u16)((i + 0x7FFFu + ((i >> 16) & 1u)) >> 16);
}

// ---------------- CSR build ----------------
__global__ __launch_bounds__(256) void k_count(const int* __restrict__ dst, int* __restrict__ cnt) {
    int e = blockIdx.x * 256 + threadIdx.x;
    atomicAdd(&cnt[dst[e]], 1);
}

__global__ __launch_bounds__(256) void k_scanA(const int* __restrict__ cnt, int* __restrict__ off,
                                               int* __restrict__ bsum) {
    __shared__ int s[256];
    int t = threadIdx.x; int i = blockIdx.x * 256 + t;
    int v = (i < N_NODES) ? cnt[i] : 0;
    s[t] = v; __syncthreads();
    for (int d = 1; d < 256; d <<= 1) {
        int x = (t >= d) ? s[t - d] : 0; __syncthreads();
        s[t] += x; __syncthreads();
    }
    if (i < N_NODES) off[i] = s[t] - v;
    if (t == 255) bsum[blockIdx.x] = s[t];
}

__global__ __launch_bounds__(512) void k_scanB(int* bsum, int nb) {
    __shared__ int s[512];
    int t = threadIdx.x;
    int v = (t < nb) ? bsum[t] : 0;
    s[t] = v; __syncthreads();
    for (int d = 1; d < 512; d <<= 1) {
        int x = (t >= d) ? s[t - d] : 0; __syncthreads();
        s[t] += x; __syncthreads();
    }
    if (t < nb) bsum[t] = s[t] - v;
}

__global__ __launch_bounds__(256) void k_scanC(int* off, const int* __restrict__ bsum) {
    int i = blockIdx.x * 256 + threadIdx.x;
    if (i < N_NODES) off[i] += bsum[blockIdx.x];
    if (i == 0) off[N_NODES] = N_EDGES;
}

__global__ __launch_bounds__(256) void k_fill(const int* __restrict__ src, const int* __restrict__ dst,
                                              const int* __restrict__ off, int* __restrict__ cur,
                                              int2* __restrict__ epk) {
    int e = blockIdx.x * 256 + threadIdx.x;
    int d = dst[e];
    int p = off[d] + atomicAdd(&cur[d], 1);
    epk[p] = make_int2(e, src[e]);
}

// ---------------- node input projection: h = x @ W + b ----------------
__global__ __launch_bounds__(256) void k_init(const float* __restrict__ x, const float* __restrict__ W,
                                              const float* __restrict__ b, float* __restrict__ h) {
    __shared__ float Ws[NODE_IN * DIM];
    __shared__ float xs[8][NODE_IN];
    int t = threadIdx.x;
    for (int i = t; i < NODE_IN * DIM; i += 256) Ws[i] = W[i];
    int nb = blockIdx.x * 8;
    for (int i = t; i < 8 * NODE_IN; i += 256) {
        int n = i / NODE_IN, j = i % NODE_IN;
        xs[n][j] = x[(size_t)(nb + n) * NODE_IN + j];
    }
    __syncthreads();
    int n = t >> 5, c = t & 31;
    float acc = b[c];
    #pragma unroll 2
    for (int j = 0; j < NODE_IN; j++) acc += xs[n][j] * Ws[j * DIM + c];
    h[(size_t)(nb + n) * DIM + c] = acc;
}

// ---------------- edge-feature GEMM (CSR-permuted rows): e[l] = ef[perm] @ We[l] ----------------
// Software-pipelined (loads of tile t+1 issued before stores of tile t), LDS-staged
// transposed output -> coalesced dwordx4 global stores, written in CSR order.
template <int NL>
__global__ __launch_bounds__(256) void k_egemm(const float* __restrict__ elen, const float* __restrict__ evec,
                                               const int2* __restrict__ epk, const float* __restrict__ We,
                                               u16* __restrict__ eout) {
    // staging: per wave, 16 rows x 320B pitch (128 bf16 cols + swizzle room)
    __shared__ u16 st[4][16 * 160];
    int tid = threadIdx.x;
    int lane = tid & 63;
    int wvl = tid >> 6;
    int wv = (blockIdx.x * 256 + tid) >> 6;
    int nw = (gridDim.x * 256) >> 6;
    int n15 = lane & 15, kb = lane >> 4;

    // B fragments: We padded to K=64, in VGPRs for the whole kernel.
    short8 bf[2][2 * NL];
    for (int s = 0; s < 2; s++) {
        for (int t = 0; t < 2 * NL; t++) {
            int n = t * 16 + n15;
            int lay = n >> 5, c = n & 31;
            short8 tmp;
            #pragma unroll
            for (int j = 0; j < 8; j++) {
                int kk = s * 32 + kb * 8 + j;
                float w = (kk < EDF) ? We[(size_t)lay * EDF * DIM + (size_t)kk * DIM + c] : 0.f;
                ((u16*)&tmp)[j] = f2bf(w);
            }
            bf[s][t] = tmp;
        }
    }

    const int NT = N_EDGES / 16;

    auto LOADA = [&](int tile, float* fv) {
        int pos = tile * 16 + n15;
        int eid = epk[pos].x;
        const float* lp = elen + (size_t)eid * 50;
        {   // s=0: cols kb*8 .. kb*8+7  (kb in 0..3 -> cols 0..31)
            const float2* p2 = (const float2*)(lp + kb * 8);
            #pragma unroll
            for (int j = 0; j < 4; j++) { float2 t2 = p2[j]; fv[2 * j] = t2.x; fv[2 * j + 1] = t2.y; }
        }
        // s=1: cols 32+kb*8
        if (kb < 2) {
            const float2* p2 = (const float2*)(lp + 32 + kb * 8);
            #pragma unroll
            for (int j = 0; j < 4; j++) { float2 t2 = p2[j]; fv[8 + 2 * j] = t2.x; fv[8 + 2 * j + 1] = t2.y; }
        } else if (kb == 2) {
            const float* vp = evec + (size_t)eid * 3;
            fv[8] = lp[48]; fv[9] = lp[49]; fv[10] = vp[0]; fv[11] = vp[1]; fv[12] = vp[2];
            fv[13] = 0.f; fv[14] = 0.f; fv[15] = 0.f;
        } else {
            #pragma unroll
            for (int j = 8; j < 16; j++) fv[j] = 0.f;
        }
    };

    float cur[16];
    if (wv < NT) LOADA(wv, cur);

    for (int tile = wv; tile < NT; tile += nw) {
        int nxt = tile + nw;
        float nx[16];
        if (nxt < NT) LOADA(nxt, nx);   // issue next loads BEFORE this tile's stores

        short8 af[2];
        #pragma unroll
        for (int s = 0; s < 2; s++) {
            short8 tmp;
            #pragma unroll
            for (int j = 0; j < 8; j++) ((u16*)&tmp)[j] = f2bf(cur[s * 8 + j]);
            af[s] = tmp;
        }

        u16* W = st[wvl];
        #pragma unroll
        for (int t = 0; t < 2 * NL; t++) {
            f32x4 z = {0.f, 0.f, 0.f, 0.f};
            z = __builtin_amdgcn_mfma_f32_16x16x32_bf16(af[0], bf[0][t], z, 0, 0, 0);
            z = __builtin_amdgcn_mfma_f32_16x16x32_bf16(af[1], bf[1][t], z, 0, 0, 0);
            int n = t * 16 + n15;
            #pragma unroll
            for (int r = 0; r < 4; r++) {
                int row = kb * 4 + r;
                // u16 index with byte-XOR ((row&12)<<3) -> u16-XOR ((row&12)<<2)
                int idx = row * 160 + (n ^ ((row & 12) << 2));
                W[idx] = f2bf(z[r]);
            }
        }
        // readback: lane -> (row = lane>>2, colblock q = lane&3), per layer 16B
        int row = lane >> 2, q = lane & 3;
        #pragma unroll
        for (int lay = 0; lay < NL; lay++) {
            int idx = row * 160 + ((lay * 32 + q * 8) ^ ((row & 12) << 2));
            short8 vblk = *(const short8*)&W[idx];
            size_t base = ((size_t)lay * N_EDGES + (size_t)tile * 16) * DIM;
            *(short8*)&eout[base + (size_t)lane * 8] = vblk;
        }

        #pragma unroll
        for (int j = 0; j < 16; j++) cur[j] = nx[j];
    }
}

// ---------------- per-layer node transform: LN + q,k,v,skip ----------------
__global__ __launch_bounds__(256) void k_node(const float* __restrict__ h,
        const float* __restrict__ g, const float* __restrict__ bta,
        const float* __restrict__ Wq, const float* __restrict__ bq,
        const float* __restrict__ Wk, const float* __restrict__ bk,
        const float* __restrict__ Wv, const float* __restrict__ bv,
        const float* __restrict__ Ws, const float* __restrict__ bs,
        float* __restrict__ qo, float* __restrict__ ko, float* __restrict__ vo, float* __restrict__ so) {
    __shared__ float WQ[DIM * DIM], WK[DIM * DIM], WV[DIM * DIM], WS[DIM * DIM];
    __shared__ float xn[8][DIM];
    int t = threadIdx.x;
    for (int i = t; i < DIM * DIM; i += 256) { WQ[i] = Wq[i]; WK[i] = Wk[i]; WV[i] = Wv[i]; WS[i] = Ws[i]; }
    int n = t >> 5, c = t & 31;
    size_t node = (size_t)blockIdx.x * 8 + n;
    float hv = h[node * DIM + c];
    float s1 = hv;
    for (int d = 1; d < 32; d <<= 1) s1 += __shfl_xor(s1, d, 64);
    float mu = s1 * (1.f / 32.f);
    float dv = hv - mu;
    float s2 = dv * dv;
    for (int d = 1; d < 32; d <<= 1) s2 += __shfl_xor(s2, d, 64);
    float inv = rsqrtf(s2 * (1.f / 32.f) + 1e-5f);
    float xv = dv * inv * g[c] + bta[c];
    xn[n][c] = xv;
    __syncthreads();
    float aq = bq[c], ak = bk[c], av = bv[c], as = bs[c];
    #pragma unroll 4
    for (int j = 0; j < DIM; j++) {
        float xj = xn[n][j];
        aq += xj * WQ[j * DIM + c];
        ak += xj * WK[j * DIM + c];
        av += xj * WV[j * DIM + c];
        as += xj * WS[j * DIM + c];
    }
    size_t o = node * DIM + c;
    qo[o] = aq; ko[o] = ak; vo[o] = av; so[o] = as;
}

// ---------------- per-layer edge aggregation: wave per node, 2 edges/iter ----------------
__global__ __launch_bounds__(256) void k_aggr(const int* __restrict__ off, const int2* __restrict__ epk,
        const u16* __restrict__ eb,
        const float* __restrict__ qb, const float* __restrict__ kb, const float* __restrict__ vb,
        const float* __restrict__ h, const float* __restrict__ sk, float* __restrict__ out) {
    int tid = threadIdx.x;
    size_t node = (size_t)blockIdx.x * 4 + (tid >> 6);
    int lane = tid & 63;
    int half = lane >> 5, c = lane & 31;
    float qc = qb[node * DIM + c];
    int o0 = off[node], o1 = off[node + 1];
    float num = 0.f, den = 0.f;
    const float scale = 0.35355339059327373f;  // 1/sqrt(8)
    for (int p0 = o0; p0 < o1; p0 += 2) {
        int p = p0 + half;
        bool act = p < o1;
        int pc = act ? p : o0;
        int sj = epk[pc].y;
        float ev = bf2f(eb[(size_t)pc * DIM + c]);
        float kv = kb[(size_t)sj * DIM + c];
        float a = qc * (kv + ev);
        a += __shfl_xor(a, 1); a += __shfl_xor(a, 2); a += __shfl_xor(a, 4);
        float ex = act ? __expf(a * scale) : 0.f;
        float vv = vb[(size_t)sj * DIM + c];
        num = fmaf(ex, vv + ev, num);
        den += ex;
    }
    num += __shfl_xor(num, 32);
    den += __shfl_xor(den, 32);
    if (half == 0) {
        size_t o = node * DIM + c;
        out[o] = h[o] + num / (den + 1e-16f) + sk[o];
    }
}

extern "C" void kernel_launch(void* const* d_in, const int* in_sizes, int n_in,
                              void* d_out, int out_size, void* d_ws, size_t ws_size,
                              hipStream_t stream) {
    const float* x    = (const float*)d_in[0];
    const int*   ei   = (const int*)d_in[1];
    const int*   src  = ei;
    const int*   dst  = ei + N_EDGES;
    const float* elen = (const float*)d_in[2];
    const float* evec = (const float*)d_in[3];
    const float* niW  = (const float*)d_in[4];
    const float* nib  = (const float*)d_in[5];
    const float* lng  = (const float*)d_in[6];
    const float* lnb  = (const float*)d_in[7];
    const float* Wq   = (const float*)d_in[8];
    const float* bq   = (const float*)d_in[9];
    const float* Wk   = (const float*)d_in[10];
    const float* bk   = (const float*)d_in[11];
    const float* Wv   = (const float*)d_in[12];
    const float* bv   = (const float*)d_in[13];
    const float* We   = (const float*)d_in[14];
    const float* Wsk  = (const float*)d_in[15];
    const float* bsk  = (const float*)d_in[16];
    float* out = (float*)d_out;

    unsigned char* w = (unsigned char*)d_ws;
    auto alloc = [&](size_t bytes) -> void* {
        void* p = (void*)w; w += (bytes + 255) & ~(size_t)255; return p;
    };
    int*   off  = (int*)alloc((N_NODES + 1) * sizeof(int));
    int*   cnt  = (int*)alloc(N_NODES * sizeof(int));       // reused as cursor
    int*   bsum = (int*)alloc(512 * sizeof(int));
    int2*  epk  = (int2*)alloc((size_t)N_EDGES * sizeof(int2));
    float* h    = (float*)alloc((size_t)N_NODES * DIM * sizeof(float));
    float* qb   = (float*)alloc((size_t)N_NODES * DIM * sizeof(float));
    float* kb   = (float*)alloc((size_t)N_NODES * DIM * sizeof(float));
    float* vb   = (float*)alloc((size_t)N_NODES * DIM * sizeof(float));
    float* skb  = (float*)alloc((size_t)N_NODES * DIM * sizeof(float));
    size_t used = (size_t)(w - (unsigned char*)d_ws);
    size_t e_full = (size_t)NLAYER * N_EDGES * DIM * sizeof(u16);
    size_t e_one  = (size_t)N_EDGES * DIM * sizeof(u16);
    bool full = (used + e_full) <= ws_size;
    u16* ebuf = (u16*)alloc(full ? e_full : e_one);

    const int EB = N_EDGES / 256;   // 12500
    const int NB = N_NODES / 8;     // 12500
    const int AB = N_NODES / 4;     // 25000
    const int nbScan = (N_NODES + 255) / 256;  // 391

    // CSR build
    hipMemsetAsync(cnt, 0, N_NODES * sizeof(int), stream);
    k_count<<<EB, 256, 0, stream>>>(dst, cnt);
    k_scanA<<<nbScan, 256, 0, stream>>>(cnt, off, bsum);
    k_scanB<<<1, 512, 0, stream>>>(bsum, nbScan);
    k_scanC<<<nbScan, 256, 0, stream>>>(off, bsum);
    hipMemsetAsync(cnt, 0, N_NODES * sizeof(int), stream);
    k_fill<<<EB, 256, 0, stream>>>(src, dst, off, cnt, epk);

    // input projection
    k_init<<<NB, 256, 0, stream>>>(x, niW, nib, h);

    // edge-feature GEMM (CSR order)
    if (full) k_egemm<4><<<2048, 256, 0, stream>>>(elen, evec, epk, We, ebuf);

    for (int l = 0; l < NLAYER; l++) {
        if (!full) k_egemm<1><<<2048, 256, 0, stream>>>(elen, evec, epk, We + (size_t)l * EDF * DIM, ebuf);
        k_node<<<NB, 256, 0, stream>>>(h, lng + l * DIM, lnb + l * DIM,
                                       Wq + (size_t)l * DIM * DIM, bq + l * DIM,
                                       Wk + (size_t)l * DIM * DIM, bk + l * DIM,
                                       Wv + (size_t)l * DIM * DIM, bv + l * DIM,
                                       Wsk + (size_t)l * DIM * DIM, bsk + l * DIM,
                                       qb, kb, vb, skb);
        const u16* el = full ? (ebuf + (size_t)l * N_EDGES * DIM) : ebuf;
        k_aggr<<<AB, 256, 0, stream>>>(off, epk, el, qb, kb, vb, h, skb,
                                       (l == NLAYER - 1) ? out : h);
    }
}

// Round 3
// 1567.467 us; speedup vs baseline: 1.3394x; 1.1933x over previous
//
#include <hip/hip_runtime.h>
#include <hip/hip_bf16.h>
#include <math.h>

#define N_NODES 100000
#define N_EDGES 3200000
#define NODE_IN 118
#define DIM 32
#define EDF 53
#define NLAYER 4

typedef __attribute__((ext_vector_type(8))) short short8;
typedef __attribute__((ext_vector_type(4))) short short4v;
typedef __attribute__((ext_vector_type(4))) float f32x4;
typedef unsigned short u16;
typedef unsigned int u32;

static __device__ __forceinline__ float bfhi2f(u32 hi) {   // bf16 in high 16 bits
    union { u32 i; float f; } x; x.i = hi; return x.f;
}
static __device__ __forceinline__ u16 f2bf(float f) {
    union { float f; u32 i; } x; x.f = f;
    u32 i = x.i;
    return (u16)((i + 0x7FFFu + ((i >> 16) & 1u)) >> 16);
}

// ---------------- CSR build ----------------
__global__ __launch_bounds__(256) void k_count(const int* __restrict__ dst, int* __restrict__ cnt) {
    int e = blockIdx.x * 256 + threadIdx.x;
    atomicAdd(&cnt[dst[e]], 1);
}

__global__ __launch_bounds__(256) void k_scanA(const int* __restrict__ cnt, int* __restrict__ off,
                                               int* __restrict__ bsum) {
    __shared__ int s[256];
    int t = threadIdx.x; int i = blockIdx.x * 256 + t;
    int v = (i < N_NODES) ? cnt[i] : 0;
    s[t] = v; __syncthreads();
    for (int d = 1; d < 256; d <<= 1) {
        int x = (t >= d) ? s[t - d] : 0; __syncthreads();
        s[t] += x; __syncthreads();
    }
    if (i < N_NODES) off[i] = s[t] - v;
    if (t == 255) bsum[blockIdx.x] = s[t];
}

__global__ __launch_bounds__(512) void k_scanB(int* bsum, int nb) {
    __shared__ int s[512];
    int t = threadIdx.x;
    int v = (t < nb) ? bsum[t] : 0;
    s[t] = v; __syncthreads();
    for (int d = 1; d < 512; d <<= 1) {
        int x = (t >= d) ? s[t - d] : 0; __syncthreads();
        s[t] += x; __syncthreads();
    }
    if (t < nb) bsum[t] = s[t] - v;
}

__global__ __launch_bounds__(256) void k_scanC(int* off, const int* __restrict__ bsum) {
    int i = blockIdx.x * 256 + threadIdx.x;
    if (i < N_NODES) off[i] += bsum[blockIdx.x];
    if (i == 0) off[N_NODES] = N_EDGES;
}

__global__ __launch_bounds__(256) void k_fill(const int* __restrict__ src, const int* __restrict__ dst,
                                              const int* __restrict__ off, int* __restrict__ cur,
                                              int* __restrict__ eidp, int* __restrict__ esrc) {
    int e = blockIdx.x * 256 + threadIdx.x;
    int d = dst[e];
    int p = off[d] + atomicAdd(&cur[d], 1);
    eidp[p] = e; esrc[p] = src[e];
}

// ---------------- node input projection: h = x @ W + b ----------------
__global__ __launch_bounds__(256) void k_init(const float* __restrict__ x, const float* __restrict__ W,
                                              const float* __restrict__ b, float* __restrict__ h) {
    __shared__ float Ws[NODE_IN * DIM];
    __shared__ float xs[8][NODE_IN];
    int t = threadIdx.x;
    for (int i = t; i < NODE_IN * DIM; i += 256) Ws[i] = W[i];
    int nb = blockIdx.x * 8;
    for (int i = t; i < 8 * NODE_IN; i += 256) {
        int n = i / NODE_IN, j = i % NODE_IN;
        xs[n][j] = x[(size_t)(nb + n) * NODE_IN + j];
    }
    __syncthreads();
    int n = t >> 5, c = t & 31;
    float acc = b[c];
    #pragma unroll 2
    for (int j = 0; j < NODE_IN; j++) acc += xs[n][j] * Ws[j * DIM + c];
    h[(size_t)(nb + n) * DIM + c] = acc;
}

// ---------------- edge-feature GEMM (CSR-permuted rows), transposed MFMA ----------------
// Computes e^T tiles: mfma(Bfrag, Afrag) -> lane holds 4 CONSECUTIVE output channels of
// one edge -> direct 8B global stores, no LDS staging at all.
template <int NL>
__global__ __launch_bounds__(256) void k_egemm(const float* __restrict__ elen, const float* __restrict__ evec,
                                               const int* __restrict__ eidp, const float* __restrict__ We,
                                               u16* __restrict__ eout) {
    int tid = threadIdx.x;
    int lane = tid & 63;
    int wv = (blockIdx.x * 256 + tid) >> 6;
    int nw = (gridDim.x * 256) >> 6;
    int n15 = lane & 15, kb = lane >> 4;

    // We fragments (K padded to 64), VGPR-resident.
    short8 bf[2][2 * NL];
    for (int s = 0; s < 2; s++) {
        for (int t = 0; t < 2 * NL; t++) {
            int n = t * 16 + n15;
            int lay = n >> 5, c = n & 31;
            short8 tmp;
            #pragma unroll
            for (int j = 0; j < 8; j++) {
                int kk = s * 32 + kb * 8 + j;
                float w = (kk < EDF) ? We[(size_t)lay * EDF * DIM + (size_t)kk * DIM + c] : 0.f;
                ((u16*)&tmp)[j] = f2bf(w);
            }
            bf[s][t] = tmp;
        }
    }

    const int NT = N_EDGES / 16;

    auto LOADA = [&](int tile, float* fv) {
        int pos = tile * 16 + n15;
        int eid = eidp[pos];
        const float* lp = elen + (size_t)eid * 50;
        {
            const float2* p2 = (const float2*)(lp + kb * 8);
            #pragma unroll
            for (int j = 0; j < 4; j++) { float2 t2 = p2[j]; fv[2 * j] = t2.x; fv[2 * j + 1] = t2.y; }
        }
        if (kb < 2) {
            const float2* p2 = (const float2*)(lp + 32 + kb * 8);
            #pragma unroll
            for (int j = 0; j < 4; j++) { float2 t2 = p2[j]; fv[8 + 2 * j] = t2.x; fv[8 + 2 * j + 1] = t2.y; }
        } else if (kb == 2) {
            float2 t2 = *(const float2*)(lp + 48);
            const float* vp = evec + (size_t)eid * 3;
            fv[8] = t2.x; fv[9] = t2.y; fv[10] = vp[0]; fv[11] = vp[1]; fv[12] = vp[2];
            fv[13] = 0.f; fv[14] = 0.f; fv[15] = 0.f;
        } else {
            #pragma unroll
            for (int j = 8; j < 16; j++) fv[j] = 0.f;
        }
    };

    float cur[16];
    if (wv < NT) LOADA(wv, cur);

    for (int tile = wv; tile < NT; tile += nw) {
        int nxt = tile + nw;
        float nx[16];
        if (nxt < NT) LOADA(nxt, nx);   // next-tile loads in flight before this tile's stores

        short8 af[2];
        #pragma unroll
        for (int s = 0; s < 2; s++) {
            short8 tmp;
            #pragma unroll
            for (int j = 0; j < 8; j++) ((u16*)&tmp)[j] = f2bf(cur[s * 8 + j]);
            af[s] = tmp;
        }

        size_t pos = (size_t)tile * 16 + n15;
        #pragma unroll
        for (int t = 0; t < 2 * NL; t++) {
            f32x4 z = {0.f, 0.f, 0.f, 0.f};
            // swapped operands: D = We^T . ef^T  -> C col = lane&15 = edge,
            // C row = kb*4 + r = channel-within-16
            z = __builtin_amdgcn_mfma_f32_16x16x32_bf16(bf[0][t], af[0], z, 0, 0, 0);
            z = __builtin_amdgcn_mfma_f32_16x16x32_bf16(bf[1][t], af[1], z, 0, 0, 0);
            int lay = t >> 1;
            int ch = (t & 1) * 16 + kb * 4;   // channel within layer, consecutive 4
            short4v sv;
            #pragma unroll
            for (int r = 0; r < 4; r++) ((u16*)&sv)[r] = f2bf(z[r]);
            *(short4v*)&eout[((size_t)lay * N_EDGES + pos) * DIM + ch] = sv;
        }

        #pragma unroll
        for (int j = 0; j < 16; j++) cur[j] = nx[j];
    }
}

// ---------------- per-layer node transform: LN + q,k,v,skip ----------------
__global__ __launch_bounds__(256) void k_node(const float* __restrict__ h,
        const float* __restrict__ g, const float* __restrict__ bta,
        const float* __restrict__ Wq, const float* __restrict__ bq,
        const float* __restrict__ Wk, const float* __restrict__ bk,
        const float* __restrict__ Wv, const float* __restrict__ bv,
        const float* __restrict__ Ws, const float* __restrict__ bs,
        float* __restrict__ qo, float* __restrict__ ko, float* __restrict__ vo, float* __restrict__ so) {
    __shared__ float WQ[DIM * DIM], WK[DIM * DIM], WV[DIM * DIM], WS[DIM * DIM];
    __shared__ float xn[8][DIM];
    int t = threadIdx.x;
    for (int i = t; i < DIM * DIM; i += 256) { WQ[i] = Wq[i]; WK[i] = Wk[i]; WV[i] = Wv[i]; WS[i] = Ws[i]; }
    int n = t >> 5, c = t & 31;
    size_t node = (size_t)blockIdx.x * 8 + n;
    float hv = h[node * DIM + c];
    float s1 = hv;
    for (int d = 1; d < 32; d <<= 1) s1 += __shfl_xor(s1, d, 64);
    float mu = s1 * (1.f / 32.f);
    float dv = hv - mu;
    float s2 = dv * dv;
    for (int d = 1; d < 32; d <<= 1) s2 += __shfl_xor(s2, d, 64);
    float inv = rsqrtf(s2 * (1.f / 32.f) + 1e-5f);
    float xv = dv * inv * g[c] + bta[c];
    xn[n][c] = xv;
    __syncthreads();
    float aq = bq[c], ak = bk[c], av = bv[c], as = bs[c];
    #pragma unroll 4
    for (int j = 0; j < DIM; j++) {
        float xj = xn[n][j];
        aq += xj * WQ[j * DIM + c];
        ak += xj * WK[j * DIM + c];
        av += xj * WV[j * DIM + c];
        as += xj * WS[j * DIM + c];
    }
    size_t o = node * DIM + c;
    qo[o] = aq; ko[o] = ak; vo[o] = av; so[o] = as;
}

// ---------------- per-layer edge aggregation: wave per node, 8 edges/iter ----------------
// lane = (edge-group eg = lane>>3, channel quad cq = lane&7 -> channels cq*4..cq*4+3)
__global__ __launch_bounds__(256) void k_aggr(const int* __restrict__ off, const int* __restrict__ esrc,
        const u16* __restrict__ eb,
        const float* __restrict__ qb, const float* __restrict__ kb, const float* __restrict__ vb,
        const float* __restrict__ h, const float* __restrict__ sk, float* __restrict__ out) {
    int tid = threadIdx.x;
    size_t node = (size_t)blockIdx.x * 4 + (tid >> 6);
    int lane = tid & 63;
    int eg = lane >> 3, cq = lane & 7, c0 = cq * 4;
    float4 qv = *(const float4*)&qb[node * DIM + c0];
    int o0 = off[node], o1 = off[node + 1];
    float4 nacc = {0.f, 0.f, 0.f, 0.f};
    float dacc = 0.f;
    const float scale = 0.35355339059327373f;  // 1/sqrt(8)
    for (int p0 = o0; p0 < o1; p0 += 8) {
        int p = p0 + eg;
        bool act = p < o1;
        int pc = act ? p : o0;
        int sj = esrc[pc];
        uint2 ebv = *(const uint2*)&eb[(size_t)pc * DIM + c0];
        float4 kv = *(const float4*)&kb[(size_t)sj * DIM + c0];
        float4 vv = *(const float4*)&vb[(size_t)sj * DIM + c0];
        float e0 = bfhi2f(ebv.x << 16), e1 = bfhi2f(ebv.x & 0xFFFF0000u);
        float e2 = bfhi2f(ebv.y << 16), e3 = bfhi2f(ebv.y & 0xFFFF0000u);
        float a = qv.x * (kv.x + e0);
        a = fmaf(qv.y, kv.y + e1, a);
        a = fmaf(qv.z, kv.z + e2, a);
        a = fmaf(qv.w, kv.w + e3, a);
        a += __shfl_xor(a, 1);           // pair covers the head's 8 channels
        float ex = act ? __expf(a * scale) : 0.f;
        nacc.x = fmaf(ex, vv.x + e0, nacc.x);
        nacc.y = fmaf(ex, vv.y + e1, nacc.y);
        nacc.z = fmaf(ex, vv.z + e2, nacc.z);
        nacc.w = fmaf(ex, vv.w + e3, nacc.w);
        dacc += ex;
    }
    // reduce across the 8 edge-groups (cq preserved)
    #pragma unroll
    for (int d = 8; d < 64; d <<= 1) {
        nacc.x += __shfl_xor(nacc.x, d);
        nacc.y += __shfl_xor(nacc.y, d);
        nacc.z += __shfl_xor(nacc.z, d);
        nacc.w += __shfl_xor(nacc.w, d);
        dacc   += __shfl_xor(dacc, d);
    }
    if (eg == 0) {
        float inv = 1.f / (dacc + 1e-16f);
        float4 hv = *(const float4*)&h[node * DIM + c0];
        float4 sv = *(const float4*)&sk[node * DIM + c0];
        float4 o;
        o.x = hv.x + nacc.x * inv + sv.x;
        o.y = hv.y + nacc.y * inv + sv.y;
        o.z = hv.z + nacc.z * inv + sv.z;
        o.w = hv.w + nacc.w * inv + sv.w;
        *(float4*)&out[node * DIM + c0] = o;
    }
}

extern "C" void kernel_launch(void* const* d_in, const int* in_sizes, int n_in,
                              void* d_out, int out_size, void* d_ws, size_t ws_size,
                              hipStream_t stream) {
    const float* x    = (const float*)d_in[0];
    const int*   ei   = (const int*)d_in[1];
    const int*   src  = ei;
    const int*   dst  = ei + N_EDGES;
    const float* elen = (const float*)d_in[2];
    const float* evec = (const float*)d_in[3];
    const float* niW  = (const float*)d_in[4];
    const float* nib  = (const float*)d_in[5];
    const float* lng  = (const float*)d_in[6];
    const float* lnb  = (const float*)d_in[7];
    const float* Wq   = (const float*)d_in[8];
    const float* bq   = (const float*)d_in[9];
    const float* Wk   = (const float*)d_in[10];
    const float* bk   = (const float*)d_in[11];
    const float* Wv   = (const float*)d_in[12];
    const float* bv   = (const float*)d_in[13];
    const float* We   = (const float*)d_in[14];
    const float* Wsk  = (const float*)d_in[15];
    const float* bsk  = (const float*)d_in[16];
    float* out = (float*)d_out;

    unsigned char* w = (unsigned char*)d_ws;
    auto alloc = [&](size_t bytes) -> void* {
        void* p = (void*)w; w += (bytes + 255) & ~(size_t)255; return p;
    };
    int*   off  = (int*)alloc((N_NODES + 1) * sizeof(int));
    int*   cnt  = (int*)alloc(N_NODES * sizeof(int));       // reused as cursor
    int*   bsum = (int*)alloc(512 * sizeof(int));
    int*   eidp = (int*)alloc((size_t)N_EDGES * sizeof(int));
    int*   esrc = (int*)alloc((size_t)N_EDGES * sizeof(int));
    float* h    = (float*)alloc((size_t)N_NODES * DIM * sizeof(float));
    float* qb   = (float*)alloc((size_t)N_NODES * DIM * sizeof(float));
    float* kb   = (float*)alloc((size_t)N_NODES * DIM * sizeof(float));
    float* vb   = (float*)alloc((size_t)N_NODES * DIM * sizeof(float));
    float* skb  = (float*)alloc((size_t)N_NODES * DIM * sizeof(float));
    size_t used = (size_t)(w - (unsigned char*)d_ws);
    size_t e_full = (size_t)NLAYER * N_EDGES * DIM * sizeof(u16);
    size_t e_one  = (size_t)N_EDGES * DIM * sizeof(u16);
    bool full = (used + e_full) <= ws_size;
    u16* ebuf = (u16*)alloc(full ? e_full : e_one);

    const int EB = N_EDGES / 256;   // 12500
    const int NB = N_NODES / 8;     // 12500
    const int AB = N_NODES / 4;     // 25000
    const int nbScan = (N_NODES + 255) / 256;  // 391

    // CSR build
    hipMemsetAsync(cnt, 0, N_NODES * sizeof(int), stream);
    k_count<<<EB, 256, 0, stream>>>(dst, cnt);
    k_scanA<<<nbScan, 256, 0, stream>>>(cnt, off, bsum);
    k_scanB<<<1, 512, 0, stream>>>(bsum, nbScan);
    k_scanC<<<nbScan, 256, 0, stream>>>(off, bsum);
    hipMemsetAsync(cnt, 0, N_NODES * sizeof(int), stream);
    k_fill<<<EB, 256, 0, stream>>>(src, dst, off, cnt, eidp, esrc);

    // input projection
    k_init<<<NB, 256, 0, stream>>>(x, niW, nib, h);

    // edge-feature GEMM (CSR order, transposed tiles, no LDS)
    if (full) k_egemm<4><<<4096, 256, 0, stream>>>(elen, evec, eidp, We, ebuf);

    for (int l = 0; l < NLAYER; l++) {
        if (!full) k_egemm<1><<<4096, 256, 0, stream>>>(elen, evec, eidp, We + (size_t)l * EDF * DIM, ebuf);
        k_node<<<NB, 256, 0, stream>>>(h, lng + l * DIM, lnb + l * DIM,
                                       Wq + (size_t)l * DIM * DIM, bq + l * DIM,
                                       Wk + (size_t)l * DIM * DIM, bk + l * DIM,
                                       Wv + (size_t)l * DIM * DIM, bv + l * DIM,
                                       Wsk + (size_t)l * DIM * DIM, bsk + l * DIM,
                                       qb, kb, vb, skb);
        const u16* el = full ? (ebuf + (size_t)l * N_EDGES * DIM) : ebuf;
        k_aggr<<<AB, 256, 0, stream>>>(off, esrc, el, qb, kb, vb, h, skb,
                                       (l == NLAYER - 1) ? out : h);
    }
}